// Round 4
// baseline (118.797 us; speedup 1.0000x reference)
//
#include <hip/hip_runtime.h>

// Embedder: counts = scatter_add(one_hot(tokens)) -> (B, DEPTH) float32
// B=1024, S=200, DEPTH=100000. Output = 409.6 MB -> write-BW bound.
//
// Two-kernel split (stream-ordered):
//   K1: pure grid-stride float4 zero-fill of d_out — mirrors rocclr
//       fillBufferAligned (no LDS, no barriers) which measures 6.6-6.9 TB/s.
//   K2: 204,800 global atomicAdds (row-private, negligible contention),
//       ~26 MB of random line RMW, latency-hidden across 3200 waves.
// This removes the fused design's per-block barrier/latency phases that
// held effective BW to 5.2 TB/s.

#define EMB_DEPTH 100000
#define EMB_SEQ   200

__global__ __launch_bounds__(256) void zero_fill_kernel(
    float4* __restrict__ out, int n4)   // n4 = total float4 count
{
    const float4 z = make_float4(0.0f, 0.0f, 0.0f, 0.0f);
    const int stride = gridDim.x * 256;
    int i = blockIdx.x * 256 + threadIdx.x;
    // 25.6M float4 / (2048*256) threads ~= 49 iterations each.
    for (; i < n4; i += stride) out[i] = z;
}

__global__ __launch_bounds__(256) void scatter_add_kernel(
    const int*   __restrict__ tokens,     // (B, S) int32
    const float* __restrict__ on_values,  // (B, S) float32
    float*       __restrict__ out,        // (B, DEPTH) float32
    int total)                            // B * S
{
    const int i = blockIdx.x * 256 + threadIdx.x;
    if (i < total) {
        const int b = i / EMB_SEQ;
        const int t = tokens[i];
        atomicAdd(out + (size_t)b * EMB_DEPTH + t, on_values[i]);
    }
}

extern "C" void kernel_launch(void* const* d_in, const int* in_sizes, int n_in,
                              void* d_out, int out_size, void* d_ws, size_t ws_size,
                              hipStream_t stream) {
    const int*   tokens    = (const int*)  d_in[0];
    const float* on_values = (const float*)d_in[1];
    float*       out       = (float*)      d_out;

    const int total = in_sizes[0];            // B*S = 204800
    const int n4    = out_size / 4;           // 25,600,000 float4

    zero_fill_kernel<<<2048, 256, 0, stream>>>((float4*)out, n4);
    scatter_add_kernel<<<(total + 255) / 256, 256, 0, stream>>>(
        tokens, on_values, out, total);
}

// Round 5
// 104.764 us; speedup vs baseline: 1.1339x; 1.1339x over previous
//
#include <hip/hip_runtime.h>

// Embedder: counts = scatter_add(one_hot(tokens)) -> (B, DEPTH) float32
// B=1024, S=200, DEPTH=100000. Output = 409.6 MB -> pure write-BW bound.
//
// Fused, LDS-free: each block owns a 1/20-row segment (20 KB). It stores
// zeros straight to global with float4 (register-sourced pure store stream,
// structurally = rocclr fillBuffer at 6.6-6.9 TB/s), one __syncthreads
// (store-ack drain at L2), then <=200 lanes do NATIVE fp32 global atomics
// (unsafeAtomicAdd -> global_atomic_add_f32; plain atomicAdd compiles to a
// CAS loop without -munsafe-fp-atomics — round-4's 50 us scatter bug) into
// the block's own just-written, still-L2-resident lines.
// Segment-local atomics => single XCD, no coherence hazard, deterministic.

#define EMB_DEPTH 100000
#define EMB_SEQ   200
#define NSEG      20
#define SEGSZ     (EMB_DEPTH / NSEG)   // 5000 floats = 20000 B (16B-aligned)

__global__ __launch_bounds__(256) void embedder_fused_kernel(
    const int*   __restrict__ tokens,     // (B, S) int32
    const float* __restrict__ on_values,  // (B, S) float32
    float*       __restrict__ out)        // (B, DEPTH) float32
{
    const int tid = threadIdx.x;
    const int b   = blockIdx.x / NSEG;
    const int seg = blockIdx.x % NSEG;
    const int lo  = seg * SEGSZ;

    // Issue token/value loads now; they complete under the store stream.
    int   t = 0;
    float v = 0.0f;
    if (tid < EMB_SEQ) {
        t = tokens[(size_t)b * EMB_SEQ + tid];
        v = on_values[(size_t)b * EMB_SEQ + tid];
    }

    // Zero the segment directly in global: 1250 float4 stores per block.
    float* rowseg = out + (size_t)b * EMB_DEPTH + lo;
    float4* out4  = reinterpret_cast<float4*>(rowseg);
    const float4 z = make_float4(0.0f, 0.0f, 0.0f, 0.0f);
    #pragma unroll
    for (int i = tid; i < SEGSZ / 4; i += 256) out4[i] = z;

    __syncthreads();  // store-acks drained (vmcnt 0) -> zeros are in L2

    // Native fp32 atomic add into our own just-written (L2-hit) segment.
    if (tid < EMB_SEQ) {
        const unsigned r = (unsigned)(t - lo);
        if (r < (unsigned)SEGSZ) {
            unsafeAtomicAdd(rowseg + r, v);   // global_atomic_add_f32
        }
    }
}

extern "C" void kernel_launch(void* const* d_in, const int* in_sizes, int n_in,
                              void* d_out, int out_size, void* d_ws, size_t ws_size,
                              hipStream_t stream) {
    const int*   tokens    = (const int*)  d_in[0];
    const float* on_values = (const float*)d_in[1];
    float*       out       = (float*)      d_out;

    const int B = in_sizes[0] / EMB_SEQ;   // 1024
    embedder_fused_kernel<<<B * NSEG, 256, 0, stream>>>(tokens, on_values, out);
}

// Round 6
// 88.762 us; speedup vs baseline: 1.3384x; 1.1803x over previous
//
#include <hip/hip_runtime.h>

// Embedder: counts = scatter_add(one_hot(tokens)) -> (B, DEPTH) float32
// B=1024, S=200, DEPTH=100000. Output = 409.6 MB -> write-BW bound.
//
// Two-phase, stream-ordered:
//   1) hipMemsetAsync zero of d_out — dispatches rocclr fillBufferAligned,
//      measured 6.4-6.9 TB/s on this chip (the fastest store stream
//      available; our hand-rolled fills and fused LDS variants all lose
//      to it by 15-25% from barrier/latency phase overhead).
//   2) scatter kernel: one thread per token, coalesced loads, native fp32
//      atomics via unsafeAtomicAdd (plain atomicAdd = CAS loop without
//      -munsafe-fp-atomics -> round-4's 50 us scatter). Row-private
//      indices => negligible contention; no barriers; waves retire with
//      atomics in flight. ~26 MB of line RMW, latency-parallel.

#define EMB_DEPTH 100000
#define EMB_SEQ   200

__global__ __launch_bounds__(256) void scatter_add_kernel(
    const int*   __restrict__ tokens,     // (B, S) int32
    const float* __restrict__ on_values,  // (B, S) float32
    float*       __restrict__ out,        // (B, DEPTH) float32
    int total)                            // B * S
{
    const int i = blockIdx.x * 256 + threadIdx.x;
    if (i < total) {
        const int   b = i / EMB_SEQ;      // magic-mul, cheap
        const int   t = tokens[i];
        const float v = on_values[i];
        unsafeAtomicAdd(out + (size_t)b * EMB_DEPTH + t, v);  // global_atomic_add_f32
    }
}

extern "C" void kernel_launch(void* const* d_in, const int* in_sizes, int n_in,
                              void* d_out, int out_size, void* d_ws, size_t ws_size,
                              hipStream_t stream) {
    const int*   tokens    = (const int*)  d_in[0];
    const float* on_values = (const float*)d_in[1];
    float*       out       = (float*)      d_out;

    const int total = in_sizes[0];        // B*S = 204800

    // Phase 1: zero 409.6 MB via rocclr's tuned fill kernel (memset node).
    hipMemsetAsync(d_out, 0, (size_t)out_size * sizeof(float), stream);

    // Phase 2: 204,800 native fp32 atomics, one per token.
    scatter_add_kernel<<<(total + 255) / 256, 256, 0, stream>>>(
        tokens, on_values, out, total);
}